// Round 1
// baseline (358.588 us; speedup 1.0000x reference)
//
#include <hip/hip_runtime.h>
#include <math.h>

#define NN 8192
#define FIN 512
#define FOUT 256

// ---------------------------------------------------------------------------
// K1: h = x @ W^T.  A = x [M,K] row-major, B = W [N,K] row-major (so C = A·B^T)
// M=8192, N=256, K=512.  64x64 tile, 256 threads, 4x4 micro-tile, BK=32.
// LDS stored K-major transposed (As[k][m]) with ld=68 to keep 16B alignment
// and spread transpose-write banks (~4-way worst case).
// ---------------------------------------------------------------------------
__global__ __launch_bounds__(256) void gemm_xwT(const float* __restrict__ A,
                                                const float* __restrict__ B,
                                                float* __restrict__ C) {
    const int K = FIN;
    __shared__ float As[32][68];
    __shared__ float Bs[32][68];

    const int bx = blockIdx.x;   // N dir: 0..3
    const int by = blockIdx.y;   // M dir: 0..127
    const int tid = threadIdx.x;
    const int tx = tid & 15;     // 0..15  (N)
    const int ty = tid >> 4;     // 0..15  (M)

    const int lr = tid >> 3;        // 0..31 loader row
    const int lk = (tid & 7) << 2;  // 0,4,...,28 loader k

    const float* Ab = A + (size_t)(by * 64) * K;
    const float* Bb = B + (size_t)(bx * 64) * K;

    float acc[4][4] = {};

    for (int k0 = 0; k0 < K; k0 += 32) {
        float4 a0 = *(const float4*)(Ab + (size_t)lr * K + k0 + lk);
        float4 a1 = *(const float4*)(Ab + (size_t)(lr + 32) * K + k0 + lk);
        float4 b0 = *(const float4*)(Bb + (size_t)lr * K + k0 + lk);
        float4 b1 = *(const float4*)(Bb + (size_t)(lr + 32) * K + k0 + lk);
        __syncthreads();
        As[lk + 0][lr] = a0.x; As[lk + 1][lr] = a0.y;
        As[lk + 2][lr] = a0.z; As[lk + 3][lr] = a0.w;
        As[lk + 0][lr + 32] = a1.x; As[lk + 1][lr + 32] = a1.y;
        As[lk + 2][lr + 32] = a1.z; As[lk + 3][lr + 32] = a1.w;
        Bs[lk + 0][lr] = b0.x; Bs[lk + 1][lr] = b0.y;
        Bs[lk + 2][lr] = b0.z; Bs[lk + 3][lr] = b0.w;
        Bs[lk + 0][lr + 32] = b1.x; Bs[lk + 1][lr + 32] = b1.y;
        Bs[lk + 2][lr + 32] = b1.z; Bs[lk + 3][lr + 32] = b1.w;
        __syncthreads();
        #pragma unroll
        for (int kk = 0; kk < 32; ++kk) {
            float4 av = *(const float4*)&As[kk][ty << 2];
            float4 bv = *(const float4*)&Bs[kk][tx << 2];
            float am[4] = {av.x, av.y, av.z, av.w};
            float bn[4] = {bv.x, bv.y, bv.z, bv.w};
            #pragma unroll
            for (int i = 0; i < 4; ++i)
                #pragma unroll
                for (int j = 0; j < 4; ++j)
                    acc[i][j] = fmaf(am[i], bn[j], acc[i][j]);
        }
    }

    const int m0 = by * 64 + (ty << 2);
    const int n0 = bx * 64 + (tx << 2);
    #pragma unroll
    for (int i = 0; i < 4; ++i) {
        float4 o = make_float4(acc[i][0], acc[i][1], acc[i][2], acc[i][3]);
        *(float4*)(C + (size_t)(m0 + i) * FOUT + n0) = o;
    }
}

// ---------------------------------------------------------------------------
// K2: d[row] = h[row,:] . a_dst   (one wave per row; 4 waves per block)
// ---------------------------------------------------------------------------
__global__ __launch_bounds__(256) void row_dot(const float* __restrict__ h,
                                               const float* __restrict__ a_dst,
                                               float* __restrict__ d) {
    const int lane = threadIdx.x & 63;
    const int wave = threadIdx.x >> 6;
    const int row = blockIdx.x * 4 + wave;
    float4 hv = *(const float4*)(h + (size_t)row * FOUT + (lane << 2));
    float4 av = *(const float4*)(a_dst + (lane << 2));
    float s = hv.x * av.x + hv.y * av.y + hv.z * av.z + hv.w * av.w;
    #pragma unroll
    for (int off = 32; off; off >>= 1) s += __shfl_down(s, off);
    if (lane == 0) d[row] = s;
}

// ---------------------------------------------------------------------------
// K3: single block: stats[0] = max(d), stats[1] = sum(exp(d - max))
// ---------------------------------------------------------------------------
__global__ __launch_bounds__(1024) void softmax_stats(const float* __restrict__ d,
                                                      float* __restrict__ stats) {
    __shared__ float red[16];
    const int tid = threadIdx.x;
    const int lane = tid & 63;
    const int wid = tid >> 6;

    const float4* dp = (const float4*)d + (size_t)tid * 2;
    float4 v0 = dp[0], v1 = dp[1];

    float m = fmaxf(fmaxf(fmaxf(v0.x, v0.y), fmaxf(v0.z, v0.w)),
                    fmaxf(fmaxf(v1.x, v1.y), fmaxf(v1.z, v1.w)));
    #pragma unroll
    for (int off = 32; off; off >>= 1) m = fmaxf(m, __shfl_xor(m, off));
    if (lane == 0) red[wid] = m;
    __syncthreads();
    if (tid == 0) {
        float mm = red[0];
        #pragma unroll
        for (int i = 1; i < 16; ++i) mm = fmaxf(mm, red[i]);
        red[0] = mm;
    }
    __syncthreads();
    const float M = red[0];
    __syncthreads();  // everyone has M; safe to reuse red[]

    float s = expf(v0.x - M) + expf(v0.y - M) + expf(v0.z - M) + expf(v0.w - M)
            + expf(v1.x - M) + expf(v1.y - M) + expf(v1.z - M) + expf(v1.w - M);
    #pragma unroll
    for (int off = 32; off; off >>= 1) s += __shfl_xor(s, off);
    if (lane == 0) red[wid] = s;
    __syncthreads();
    if (tid == 0) {
        float ss = 0.f;
        #pragma unroll
        for (int i = 0; i < 16; ++i) ss += red[i];
        stats[0] = M;
        stats[1] = ss;
    }
}

// ---------------------------------------------------------------------------
// K4: v[c] += sum_{j in block chunk} exp(d[j]-M) * h[j,c]  (64 blocks x 128 rows)
// ---------------------------------------------------------------------------
__global__ __launch_bounds__(256) void weighted_sum(const float* __restrict__ h,
                                                    const float* __restrict__ d,
                                                    const float* __restrict__ stats,
                                                    float* __restrict__ v) {
    __shared__ float w[128];
    const int tid = threadIdx.x;
    const int r0 = blockIdx.x * 128;
    const float M = stats[0];
    if (tid < 128) w[tid] = expf(d[r0 + tid] - M);
    __syncthreads();
    float acc = 0.f;
    #pragma unroll 8
    for (int j = 0; j < 128; ++j)
        acc = fmaf(w[j], h[(size_t)(r0 + j) * FOUT + tid], acc);
    atomicAdd(&v[tid], acc);
}

// ---------------------------------------------------------------------------
// K5: out[i,c] = v[c] / sumexp   (all rows identical)
// ---------------------------------------------------------------------------
__global__ __launch_bounds__(256) void broadcast_out(const float* __restrict__ v,
                                                     const float* __restrict__ stats,
                                                     float* __restrict__ out) {
    const int idx = blockIdx.x * 256 + threadIdx.x;  // float4 index
    const float inv = 1.0f / stats[1];
    float4 vv = ((const float4*)v)[idx & 63];  // 64 float4 per row
    vv.x *= inv; vv.y *= inv; vv.z *= inv; vv.w *= inv;
    ((float4*)out)[idx] = vv;
}

extern "C" void kernel_launch(void* const* d_in, const int* in_sizes, int n_in,
                              void* d_out, int out_size, void* d_ws, size_t ws_size,
                              hipStream_t stream) {
    const float* x = (const float*)d_in[0];
    // d_in[1] = adj — mathematically unused by the reference
    const float* W = (const float*)d_in[2];
    const float* a = (const float*)d_in[3];
    float* out = (float*)d_out;

    // h (8192x256 fp32) staged in d_out itself (same size); small ws scratch:
    float* ws    = (float*)d_ws;
    float* dvec  = ws;                // 8192 floats
    float* stats = ws + NN;           // 16 floats (2 used)
    float* v     = ws + NN + 16;      // 256 floats

    hipMemsetAsync(v, 0, FOUT * sizeof(float), stream);

    gemm_xwT<<<dim3(FOUT / 64, NN / 64), 256, 0, stream>>>(x, W, out);
    row_dot<<<NN / 4, 256, 0, stream>>>(out, a + FOUT, dvec);
    softmax_stats<<<1, 1024, 0, stream>>>(dvec, stats);
    weighted_sum<<<NN / 128, 256, 0, stream>>>(out, dvec, stats, v);
    broadcast_out<<<(NN * FOUT / 4) / 256, 256, 0, stream>>>(v, stats, out);
}

// Round 2
// 330.160 us; speedup vs baseline: 1.0861x; 1.0861x over previous
//
#include <hip/hip_runtime.h>
#include <math.h>

#define NN 8192
#define FIN 512
#define FOUT 256

// Math: softmax(s_i + d_j, axis=1) is independent of i (row-constant s_i
// cancels), so out[i,:] = (sum_j exp(d_j - M) h[j,:]) / S for all i.
// Further: d = x @ (W^T a_dst) = x @ g, and
//          v = sum_j w_j h[j,:] = (sum_j w_j x[j,:]) @ W^T = W @ u.
// => no N x F_OUT GEMM needed at all; h is never materialized.

// ---------------------------------------------------------------------------
// K1: g[k] = sum_c W[c,k] * a_dst[c].   8 blocks x 256 thr; 4 c-slices of 64.
// ---------------------------------------------------------------------------
__global__ __launch_bounds__(256) void compute_g(const float* __restrict__ W,
                                                 const float* __restrict__ a_dst,
                                                 float* __restrict__ g) {
    __shared__ float red[4][64];
    const int tid = threadIdx.x;
    const int kl = tid & 63;
    const int cp = tid >> 6;            // 0..3
    const int k = blockIdx.x * 64 + kl; // 0..511
    float s = 0.f;
    #pragma unroll 8
    for (int c = cp * 64; c < cp * 64 + 64; ++c)
        s = fmaf(W[(size_t)c * FIN + k], a_dst[c], s);
    red[cp][kl] = s;
    __syncthreads();
    if (cp == 0) g[k] = red[0][kl] + red[1][kl] + red[2][kl] + red[3][kl];
}

// ---------------------------------------------------------------------------
// K2: d[row] = x[row,:] . g    (1 wave per row, 4 waves/block, 2048 blocks)
// ---------------------------------------------------------------------------
__global__ __launch_bounds__(256) void rowdot_xg(const float* __restrict__ x,
                                                 const float* __restrict__ g,
                                                 float* __restrict__ d) {
    __shared__ float gs[FIN];
    const int tid = threadIdx.x;
    if (tid < 128) ((float4*)gs)[tid] = ((const float4*)g)[tid];
    __syncthreads();
    const int lane = tid & 63;
    const int wave = tid >> 6;
    const int row = blockIdx.x * 4 + wave;
    const float4* xr = (const float4*)(x + (size_t)row * FIN);
    float4 x0 = xr[lane * 2], x1 = xr[lane * 2 + 1];
    float4 g0 = ((const float4*)gs)[lane * 2], g1 = ((const float4*)gs)[lane * 2 + 1];
    float s = x0.x * g0.x + x0.y * g0.y + x0.z * g0.z + x0.w * g0.w
            + x1.x * g1.x + x1.y * g1.y + x1.z * g1.z + x1.w * g1.w;
    #pragma unroll
    for (int off = 32; off; off >>= 1) s += __shfl_down(s, off);
    if (lane == 0) d[row] = s;
}

// ---------------------------------------------------------------------------
// K3: stats[0]=max(d), stats[1]=sum(exp(d-max)); also zero u[512] for K4.
// ---------------------------------------------------------------------------
__global__ __launch_bounds__(1024) void softmax_stats(const float* __restrict__ d,
                                                      float* __restrict__ stats,
                                                      float* __restrict__ u) {
    __shared__ float red[16];
    const int tid = threadIdx.x;
    const int lane = tid & 63;
    const int wid = tid >> 6;

    if (tid < FIN) u[tid] = 0.f;

    const float4* dp = (const float4*)d + (size_t)tid * 2;
    float4 v0 = dp[0], v1 = dp[1];

    float m = fmaxf(fmaxf(fmaxf(v0.x, v0.y), fmaxf(v0.z, v0.w)),
                    fmaxf(fmaxf(v1.x, v1.y), fmaxf(v1.z, v1.w)));
    #pragma unroll
    for (int off = 32; off; off >>= 1) m = fmaxf(m, __shfl_xor(m, off));
    if (lane == 0) red[wid] = m;
    __syncthreads();
    if (tid == 0) {
        float mm = red[0];
        #pragma unroll
        for (int i = 1; i < 16; ++i) mm = fmaxf(mm, red[i]);
        red[0] = mm;
    }
    __syncthreads();
    const float M = red[0];
    __syncthreads();

    float s = expf(v0.x - M) + expf(v0.y - M) + expf(v0.z - M) + expf(v0.w - M)
            + expf(v1.x - M) + expf(v1.y - M) + expf(v1.z - M) + expf(v1.w - M);
    #pragma unroll
    for (int off = 32; off; off >>= 1) s += __shfl_xor(s, off);
    if (lane == 0) red[wid] = s;
    __syncthreads();
    if (tid == 0) {
        float ss = 0.f;
        #pragma unroll
        for (int i = 0; i < 16; ++i) ss += red[i];
        stats[0] = M;
        stats[1] = ss;
    }
}

// ---------------------------------------------------------------------------
// K4: u[k] += sum_{j in chunk} exp(d[j]-M) * x[j,k]   (64 blocks x 128 rows)
// ---------------------------------------------------------------------------
__global__ __launch_bounds__(512) void weighted_colsum(const float* __restrict__ x,
                                                       const float* __restrict__ d,
                                                       const float* __restrict__ stats,
                                                       float* __restrict__ u) {
    __shared__ float w[128];
    const int tid = threadIdx.x;
    const int r0 = blockIdx.x * 128;
    const float M = stats[0];
    if (tid < 128) w[tid] = expf(d[r0 + tid] - M);
    __syncthreads();
    float acc = 0.f;
    #pragma unroll 8
    for (int j = 0; j < 128; ++j)
        acc = fmaf(w[j], x[(size_t)(r0 + j) * FIN + tid], acc);
    atomicAdd(&u[tid], acc);
}

// ---------------------------------------------------------------------------
// K5: vs[c] = (W[c,:] . u) / S     (1 wave per c, 4 waves/block, 64 blocks)
// ---------------------------------------------------------------------------
__global__ __launch_bounds__(256) void compute_v(const float* __restrict__ W,
                                                 const float* __restrict__ u,
                                                 const float* __restrict__ stats,
                                                 float* __restrict__ vs) {
    __shared__ float us[FIN];
    const int tid = threadIdx.x;
    if (tid < 128) ((float4*)us)[tid] = ((const float4*)u)[tid];
    __syncthreads();
    const int lane = tid & 63;
    const int wave = tid >> 6;
    const int c = blockIdx.x * 4 + wave;
    const float4* wr = (const float4*)(W + (size_t)c * FIN);
    float4 w0 = wr[lane * 2], w1 = wr[lane * 2 + 1];
    float4 u0 = ((const float4*)us)[lane * 2], u1 = ((const float4*)us)[lane * 2 + 1];
    float s = w0.x * u0.x + w0.y * u0.y + w0.z * u0.z + w0.w * u0.w
            + w1.x * u1.x + w1.y * u1.y + w1.z * u1.z + w1.w * u1.w;
    #pragma unroll
    for (int off = 32; off; off >>= 1) s += __shfl_down(s, off);
    if (lane == 0) vs[c] = s / stats[1];
}

// ---------------------------------------------------------------------------
// K6: out[i,:] = vs  (all 8192 rows identical; pure 8 MB store)
// ---------------------------------------------------------------------------
__global__ __launch_bounds__(256) void broadcast_out(const float* __restrict__ vs,
                                                     float* __restrict__ out) {
    const int idx = blockIdx.x * 256 + threadIdx.x;  // float4 index
    float4 vv = ((const float4*)vs)[idx & 63];       // 64 float4 per row
    ((float4*)out)[idx] = vv;
}

extern "C" void kernel_launch(void* const* d_in, const int* in_sizes, int n_in,
                              void* d_out, int out_size, void* d_ws, size_t ws_size,
                              hipStream_t stream) {
    const float* x = (const float*)d_in[0];
    // d_in[1] = adj — mathematically unused by the reference (softmax row-dim
    //            cancellation; adj never enters the computation at all)
    const float* W = (const float*)d_in[2];
    const float* a = (const float*)d_in[3];
    float* out = (float*)d_out;

    float* ws    = (float*)d_ws;
    float* dvec  = ws;                 // 8192
    float* stats = ws + NN;            // 16
    float* g     = ws + NN + 16;       // 512
    float* u     = ws + NN + 16 + 512; // 512
    float* vs    = ws + NN + 16 + 1024;// 256

    compute_g<<<8, 256, 0, stream>>>(W, a + FOUT, g);
    rowdot_xg<<<NN / 4, 256, 0, stream>>>(x, g, dvec);
    softmax_stats<<<1, 1024, 0, stream>>>(dvec, stats, u);
    weighted_colsum<<<NN / 128, 512, 0, stream>>>(x, dvec, stats, u);
    compute_v<<<FOUT / 4, 256, 0, stream>>>(W, u, stats, vs);
    broadcast_out<<<(NN * FOUT / 4) / 256, 256, 0, stream>>>(vs, out);
}